// Round 5
// baseline (7968.509 us; speedup 1.0000x reference)
//
#include <hip/hip_runtime.h>
#include <hip/hip_bf16.h>
#include <math.h>

#define Bz 64
#define Tz 256
#define Dz 512
#define Hz 1024
#define G3 3072
#define NBK 64      // blocks in persistent recurrence kernel

typedef short bf16x8 __attribute__((ext_vector_type(8)));
typedef float f32x4 __attribute__((ext_vector_type(4)));

__device__ __forceinline__ float sigm(float x){ return 1.0f/(1.0f+expf(-x)); }

__device__ __forceinline__ unsigned short f2b(float f){
  union{float f;unsigned u;}v; v.f=f;
  unsigned r = v.u + 0x7FFFu + ((v.u>>16)&1u);
  return (unsigned short)(r>>16);
}
__device__ __forceinline__ float b2f(unsigned short s){
  union{unsigned u;float f;}v; v.u = ((unsigned)s)<<16; return v.f;
}
__device__ __forceinline__ unsigned pk2(float a, float b){
  return (unsigned)f2b(a) | ((unsigned)f2b(b)<<16);
}

// ---- coherent (agent-scope, sc1; no-fence) access helpers ----
__device__ __forceinline__ unsigned long long cld64(const void* p){
  return __hip_atomic_load((const unsigned long long*)p, __ATOMIC_RELAXED, __HIP_MEMORY_SCOPE_AGENT);
}
__device__ __forceinline__ void cst64(void* p, unsigned long long v){
  __hip_atomic_store((unsigned long long*)p, v, __ATOMIC_RELAXED, __HIP_MEMORY_SCOPE_AGENT);
}
__device__ __forceinline__ bf16x8 cldb8(const unsigned short* p){
  union { unsigned long long u[2]; bf16x8 v; } U;
  U.u[0] = cld64(p); U.u[1] = cld64(p+4);
  return U.v;
}

// ---- leaderless grid barrier: arrival flags + every block polls all 64 ----
__device__ __forceinline__ void gbar(int* flags, int ph) {
  __syncthreads();   // drains each wave's vmcnt -> all sc1 data stores agent-visible
  if (threadIdx.x == 0)
    __hip_atomic_store(flags + blockIdx.x, ph, __ATOMIC_RELAXED, __HIP_MEMORY_SCOPE_AGENT);
  if (threadIdx.x < 64) {
    while (!__all(__hip_atomic_load(flags + threadIdx.x, __ATOMIC_RELAXED,
                                    __HIP_MEMORY_SCOPE_AGENT) >= ph))
      __builtin_amdgcn_s_sleep(1);
  }
  __syncthreads();
}

// ---------------- f32 skinny GEMM core (kP only, tiny) ----------------
#define KCHUNK 128
#define LDA 132
template<int COLS, int KDIM>
__device__ __forceinline__ void gemm_core(const float* __restrict__ Abase, int rowStride,
                                          const float* __restrict__ W,
                                          int jc0, int b, int tid,
                                          float* __restrict__ acc, float* __restrict__ lds)
{
#pragma unroll
  for (int c=0;c<COLS;c++) acc[c]=0.0f;
  constexpr int C4 = KCHUNK/4;
  for (int kb=0; kb<KDIM; kb+=KCHUNK) {
    __syncthreads();
    for (int i = tid; i < Bz*C4; i += 256) {
      int r  = i / C4;
      int c4 = i % C4;
      float4 v = *(const float4*)(Abase + (size_t)r*rowStride + kb + c4*4);
      *(float4*)(lds + r*LDA + c4*4) = v;
    }
    __syncthreads();
    const float* arow  = lds + b*LDA;
    const float* wbase = W + (size_t)jc0*KDIM + kb;
    for (int k=0;k<KCHUNK;k+=4) {
      float4 a = *(const float4*)(arow + k);
#pragma unroll
      for (int c=0;c<COLS;c++) {
        float4 w = *(const float4*)(wbase + (size_t)c*KDIM + k);
        acc[c] = fmaf(a.x,w.x,fmaf(a.y,w.y,fmaf(a.z,w.z,fmaf(a.w,w.w,acc[c]))));
      }
    }
  }
}

// ---- kP: pT[j][b] = ctx[b]·Wp[j] + bp[j] + bi[j] + (j<2H ? bh[j] : bc[j-2H])
__global__ __launch_bounds__(256)
void kP(const float* __restrict__ ctx, const float* __restrict__ Wp,
        const float* __restrict__ bp, const float* __restrict__ bh,
        const float* __restrict__ bc, const float* __restrict__ bi,
        float* __restrict__ pT)
{
  __shared__ float lds[Bz*LDA];
  int tid=threadIdx.x; int b=tid&63;
  int wv=__builtin_amdgcn_readfirstlane(tid>>6);
  int jc0 = blockIdx.x*16 + wv*4;
  float acc[4];
  gemm_core<4, Hz>(ctx, Hz, Wp, jc0, b, tid, acc, lds);
#pragma unroll
  for(int c=0;c<4;c++){
    int j=jc0+c;
    float v = acc[c] + bp[j] + bi[j] + (j < 2*Hz ? bh[j] : bc[j-2*Hz]);
    pT[(size_t)j*64 + b] = v;
  }
}

// ---- kI: hB[b][j] = bf16(h0[b][j]).  64 blocks x 256 thr.
__global__ __launch_bounds__(256)
void kI(const float* __restrict__ h0, unsigned short* __restrict__ hB)
{
  int b = blockIdx.x;
  int j = threadIdx.x*4;
  float4 v = *(const float4*)(h0 + (size_t)b*Hz + j);
  unsigned long long pk = (unsigned long long)pk2(v.x,v.y)
                        | ((unsigned long long)pk2(v.z,v.w) << 32);
  *(unsigned long long*)(hB + (size_t)b*Hz + j) = pk;
}

// ---- kAm: MFMA input GEMM. igT[t][j][b] = bf16( x[b,t]·Wi[j] + pT[j][b] )
__global__ __launch_bounds__(1024)
void kAm(const float* __restrict__ x, const float* __restrict__ Wi,
         const float* __restrict__ pT, unsigned short* __restrict__ igT)
{
  __shared__ unsigned short wiF[4*16*64*8];  // 64 KB
  __shared__ unsigned short xs[64*528];      // 66 KB
  __shared__ unsigned short igs[64*64];      // 8 KB
  const int tid = threadIdx.x;
  const int lane = tid & 63;
  const int w = __builtin_amdgcn_readfirstlane(tid >> 6);
  const int j0 = blockIdx.x * 64;
  const int t0 = blockIdx.y * 16;
  const int mt = w >> 2, nt = w & 3;
  const int bb = nt*16 + (lane & 15);
  const int q  = lane >> 4;
  const int jl = mt*16 + q*4;

  for (int idx = tid; idx < 4096; idx += 1024) {
    int mt2 = idx >> 10;
    int ks = (idx >> 6) & 15;
    int ln = idx & 63;
    int j = j0 + mt2*16 + (ln & 15);
    int k = ks*32 + (ln >> 4)*8;
    const float* s = Wi + (size_t)j*Dz + k;
    unsigned short* d = wiF + (size_t)idx*8;
#pragma unroll
    for (int qq=0;qq<8;qq++) d[qq] = f2b(s[qq]);
  }
  float pv[4];
#pragma unroll
  for (int r=0;r<4;r++) pv[r] = pT[(size_t)(j0+jl+r)*64 + bb];

  for (int it=0; it<16; it++) {
    int t = t0 + it;
    __syncthreads();
    for (int i = tid; i < 64*32; i += 1024) {
      int b = i >> 5, c = i & 31;
      const float* s = x + ((size_t)b*Tz + t)*Dz + c*16;
      unsigned* d = (unsigned*)(xs + (size_t)b*528 + c*16);
      float4 v0 = *(const float4*)(s);
      float4 v1 = *(const float4*)(s+4);
      float4 v2 = *(const float4*)(s+8);
      float4 v3 = *(const float4*)(s+12);
      d[0]=pk2(v0.x,v0.y); d[1]=pk2(v0.z,v0.w);
      d[2]=pk2(v1.x,v1.y); d[3]=pk2(v1.z,v1.w);
      d[4]=pk2(v2.x,v2.y); d[5]=pk2(v2.z,v2.w);
      d[6]=pk2(v3.x,v3.y); d[7]=pk2(v3.z,v3.w);
    }
    __syncthreads();
    f32x4 acc = {0.f,0.f,0.f,0.f};
    const unsigned short* bsrc = xs + (size_t)bb*528 + q*8;
#pragma unroll
    for (int ks=0; ks<16; ks++) {
      bf16x8 a = *(const bf16x8*)(wiF + ((size_t)(mt*16+ks)*64 + lane)*8);
      bf16x8 b = *(const bf16x8*)(bsrc + ks*32);
      acc = __builtin_amdgcn_mfma_f32_16x16x32_bf16(a, b, acc, 0, 0, 0);
    }
#pragma unroll
    for (int r=0;r<4;r++) igs[(size_t)(jl+r)*64 + bb] = f2b(acc[r] + pv[r]);
    __syncthreads();
    if (tid < 512) {
      int j = tid >> 3, seg = tid & 7;
      *(uint4*)(igT + ((size_t)t*G3 + j0 + j)*64 + seg*8) =
        *(const uint4*)(igs + (size_t)j*64 + seg*8);
    }
  }
}

// ---- krec: persistent MFMA recurrence, 64 blocks x 1024 threads.
// Block n owns: phase1 r-cols [16n,16n+16) + i-cols 1024+[16n,16n+16); phase2 h-cols [16n,16n+16).
// h-state (f32) and input-gate live in block-local LDS. Only hB/rhB (bf16 [b][k]) cross blocks (sc1).
__global__ __launch_bounds__(1024, 4)
void krec(const float* __restrict__ Wh, const float* __restrict__ Wc,
          const unsigned short* __restrict__ igT,
          unsigned short* __restrict__ hB, unsigned short* __restrict__ rhB,
          float* __restrict__ out, int* flags)
{
  __shared__ unsigned short whF[2*32*64*8];  // 64 KB  (16 r-rows + 16 i-rows, frag-swizzled)
  __shared__ unsigned short wcF[32*64*8];    // 32 KB  (16 n-rows)
  __shared__ float red[16*64*4];             // 16 KB  split-K reduction
  __shared__ float hFl[16*65];               // local h state  [j_local][b], pad 65
  __shared__ float iTl[16*65];               // local input gate
  const int tid = threadIdx.x;
  const int lane = tid & 63;
  const int w = __builtin_amdgcn_readfirstlane(tid >> 6);
  const int n = blockIdx.x;

  // fragment-swizzle weight slices (f32 -> bf16), one-time.
  // whF tile mt=0: r-rows j=16n+(ln&15); mt=1: i-rows j=1024+16n+(ln&15)
  for (int idx = tid; idx < 4096; idx += 1024) {
    int mt = idx >> 11;
    int ks = (idx >> 6) & 31;
    int ln = idx & 63;
    int j = (mt ? 1024 + 16*n : 16*n) + (ln & 15);
    int k = ks*32 + (ln >> 4)*8;
    const float* s = Wh + (size_t)j*Hz + k;
    unsigned short* d = whF + (size_t)idx*8;
#pragma unroll
    for (int qq=0;qq<8;qq++) d[qq] = f2b(s[qq]);
  }
  for (int idx = tid; idx < 2048; idx += 1024) {
    int ks = (idx >> 6) & 31;
    int ln = idx & 63;
    int j = n*16 + (ln & 15);
    int k = ks*32 + (ln >> 4)*8;
    const float* s = Wc + (size_t)j*Hz + k;
    unsigned short* d = wcF + (size_t)idx*8;
#pragma unroll
    for (int qq=0;qq<8;qq++) d[qq] = f2b(s[qq]);
  }
  { // init local h state from h0-transpose slice (via global hB? no: exact f32 from Wh source... use igT? use h0 via out? -> load from global h0 is gone; reuse hB would lose precision)
  }
  // NOTE: hFl must be exact f32 h0; we read it from the f32 source: passed via `out` tail? No —
  // we read h0 directly (extra kernel arg below).
  __syncthreads();

  // (init moved here so it can use the extra arg; see signature change note)
  // -- placeholder, real init done in loop prologue below --

  for (int t=0;t<Tz;t++) {
    const unsigned short* igt = igT + (size_t)t*G3*64;
    // ---------- phase 1: gates r,i ----------
    {
      int tp = w & 7, kh = w >> 3;        // 8 tiles (mt,nt) x split-K-2
      int mt = tp >> 2, nt = tp & 3;
      int bb = nt*16 + (lane & 15);
      int q  = lane >> 4;
      int jl = q*4;                       // col within the 16-col tile
      float igv[4], hv[4];
      if (w < 8) {
        int jg = (w < 4 ? 16*n : 1024 + 16*n) + jl;   // global gate col
#pragma unroll
        for (int r=0;r<4;r++) igv[r] = b2f(igt[(size_t)(jg+r)*64 + bb]);
        if (w < 4) {
#pragma unroll
          for (int r=0;r<4;r++) hv[r] = hFl[(jl+r)*65 + bb];
        }
      }
      // bulk prefetch B fragments (h state, sc1)
      const unsigned short* bsrc = hB + (size_t)bb*Hz + q*8;
      bf16x8 bfr[16];
#pragma unroll
      for (int ks=0; ks<16; ks++) bfr[ks] = cldb8(bsrc + (size_t)(kh*16+ks)*32);
      f32x4 acc = {0.f,0.f,0.f,0.f};
      const unsigned short* asrc = whF + ((size_t)(mt*32 + kh*16)*64 + lane)*8;
#pragma unroll
      for (int ks=0; ks<16; ks++) {
        bf16x8 a = *(const bf16x8*)(asrc + (size_t)ks*64*8);
        acc = __builtin_amdgcn_mfma_f32_16x16x32_bf16(a, bfr[ks], acc, 0, 0, 0);
      }
      *(f32x4*)(red + ((size_t)w*64 + lane)*4) = acc;
      __syncthreads();
      if (w < 8) {
        f32x4 o  = *(const f32x4*)(red + ((size_t)w*64+lane)*4);
        f32x4 p2 = *(const f32x4*)(red + ((size_t)(w+8)*64+lane)*4);
        if (w < 4) {          // r-gates -> rhB (broadcast)
          unsigned long long pk = 0;
#pragma unroll
          for (int r=0;r<4;r++) {
            float g = sigm(o[r] + p2[r] + igv[r]);
            pk |= (unsigned long long)f2b(g * hv[r]) << (16*r);
          }
          cst64(rhB + (size_t)bb*Hz + 16*n + jl, pk);
        } else {              // i-gates -> local LDS
#pragma unroll
          for (int r=0;r<4;r++) iTl[(jl+r)*65 + bb] = sigm(o[r] + p2[r] + igv[r]);
        }
      }
    }
    gbar(flags, 2*t+1);
    // ---------- phase 2: n-gate + h update ----------
    {
      int nt = w & 3, kq = w >> 2;        // 4 tiles x split-K-4
      int bb = nt*16 + (lane & 15);
      int q  = lane >> 4;
      int jl = q*4;
      float igv[4];
      if (w < 4) {
#pragma unroll
        for (int r=0;r<4;r++) igv[r] = b2f(igt[(size_t)(2048 + 16*n + jl + r)*64 + bb]);
      }
      const unsigned short* bsrc = rhB + (size_t)bb*Hz + q*8;
      bf16x8 bfr[8];
#pragma unroll
      for (int ks=0; ks<8; ks++) bfr[ks] = cldb8(bsrc + (size_t)(kq*8+ks)*32);
      f32x4 acc = {0.f,0.f,0.f,0.f};
#pragma unroll
      for (int ks=0; ks<8; ks++) {
        bf16x8 a = *(const bf16x8*)(wcF + ((size_t)(kq*8+ks)*64 + lane)*8);
        acc = __builtin_amdgcn_mfma_f32_16x16x32_bf16(a, bfr[ks], acc, 0, 0, 0);
      }
      *(f32x4*)(red + ((size_t)w*64 + lane)*4) = acc;
      __syncthreads();
      if (w < 4) {
        f32x4 s0 = *(const f32x4*)(red + ((size_t)w*64+lane)*4);
        f32x4 s1 = *(const f32x4*)(red + ((size_t)(w+4)*64+lane)*4);
        f32x4 s2 = *(const f32x4*)(red + ((size_t)(w+8)*64+lane)*4);
        f32x4 s3 = *(const f32x4*)(red + ((size_t)(w+12)*64+lane)*4);
        float hy4[4];
        unsigned long long pk = 0;
#pragma unroll
        for (int r=0;r<4;r++) {
          float g  = s0[r]+s1[r]+s2[r]+s3[r] + igv[r];
          float ng = tanhf(g);
          float hp = hFl[(jl+r)*65 + bb];
          float iv = iTl[(jl+r)*65 + bb];
          float hy = hp + iv*(ng - hp);
          hy4[r] = hy;
          hFl[(jl+r)*65 + bb] = hy;
          pk |= (unsigned long long)f2b(hy) << (16*r);
        }
        cst64(hB + (size_t)bb*Hz + 16*n + jl, pk);
        float4 ov; ov.x=hy4[0]; ov.y=hy4[1]; ov.z=hy4[2]; ov.w=hy4[3];
        *(float4*)(out + ((size_t)bb*Tz + t)*Hz + 16*n + jl) = ov;
      }
    }
    gbar(flags, 2*t+2);
  }
  // final hidden state: out2[b][16n+j] = hFl[j][b]
  {
    int j = tid >> 6, b = tid & 63;
    out[(size_t)Bz*Tz*Hz + (size_t)b*Hz + 16*n + j] = hFl[j*65 + b];
  }
}

// krec needs exact f32 h0 for hFl init — do it via a tiny pre-pass writing a
// global staging buffer in [j_local-slice] order? Simpler: init inside krec from h0.
__global__ __launch_bounds__(1024, 4)
void krec_full(const float* __restrict__ h0,
               const float* __restrict__ Wh, const float* __restrict__ Wc,
               const unsigned short* __restrict__ igT,
               unsigned short* __restrict__ hB, unsigned short* __restrict__ rhB,
               float* __restrict__ out, int* flags)
{
  // delegated: identical body lives in krec, but krec lacks h0. This wrapper is the
  // real kernel; krec above is unused (kept to preserve structure documentation).
  // --- full implementation ---
  __shared__ unsigned short whF[2*32*64*8];
  __shared__ unsigned short wcF[32*64*8];
  __shared__ float red[16*64*4];
  __shared__ float hFl[16*65];
  __shared__ float iTl[16*65];
  const int tid = threadIdx.x;
  const int lane = tid & 63;
  const int w = __builtin_amdgcn_readfirstlane(tid >> 6);
  const int n = blockIdx.x;

  for (int idx = tid; idx < 4096; idx += 1024) {
    int mt = idx >> 11;
    int ks = (idx >> 6) & 31;
    int ln = idx & 63;
    int j = (mt ? 1024 + 16*n : 16*n) + (ln & 15);
    int k = ks*32 + (ln >> 4)*8;
    const float* s = Wh + (size_t)j*Hz + k;
    unsigned short* d = whF + (size_t)idx*8;
#pragma unroll
    for (int qq=0;qq<8;qq++) d[qq] = f2b(s[qq]);
  }
  for (int idx = tid; idx < 2048; idx += 1024) {
    int ks = (idx >> 6) & 31;
    int ln = idx & 63;
    int j = n*16 + (ln & 15);
    int k = ks*32 + (ln >> 4)*8;
    const float* s = Wc + (size_t)j*Hz + k;
    unsigned short* d = wcF + (size_t)idx*8;
#pragma unroll
    for (int qq=0;qq<8;qq++) d[qq] = f2b(s[qq]);
  }
  { // hFl[j][b] = h0[b][16n+j]
    int j = tid >> 6, b = tid & 63;
    hFl[j*65 + b] = h0[(size_t)b*Hz + 16*n + j];
  }
  __syncthreads();

  for (int t=0;t<Tz;t++) {
    const unsigned short* igt = igT + (size_t)t*G3*64;
    {
      int tp = w & 7, kh = w >> 3;
      int mt = tp >> 2, nt = tp & 3;
      int bb = nt*16 + (lane & 15);
      int q  = lane >> 4;
      int jl = q*4;
      float igv[4], hv[4];
      if (w < 8) {
        int jg = (w < 4 ? 16*n : 1024 + 16*n) + jl;
#pragma unroll
        for (int r=0;r<4;r++) igv[r] = b2f(igt[(size_t)(jg+r)*64 + bb]);
        if (w < 4) {
#pragma unroll
          for (int r=0;r<4;r++) hv[r] = hFl[(jl+r)*65 + bb];
        }
      }
      const unsigned short* bsrc = hB + (size_t)bb*Hz + q*8;
      bf16x8 bfr[16];
#pragma unroll
      for (int ks=0; ks<16; ks++) bfr[ks] = cldb8(bsrc + (size_t)(kh*16+ks)*32);
      f32x4 acc = {0.f,0.f,0.f,0.f};
      const unsigned short* asrc = whF + ((size_t)(mt*32 + kh*16)*64 + lane)*8;
#pragma unroll
      for (int ks=0; ks<16; ks++) {
        bf16x8 a = *(const bf16x8*)(asrc + (size_t)ks*64*8);
        acc = __builtin_amdgcn_mfma_f32_16x16x32_bf16(a, bfr[ks], acc, 0, 0, 0);
      }
      *(f32x4*)(red + ((size_t)w*64 + lane)*4) = acc;
      __syncthreads();
      if (w < 8) {
        f32x4 o  = *(const f32x4*)(red + ((size_t)w*64+lane)*4);
        f32x4 p2 = *(const f32x4*)(red + ((size_t)(w+8)*64+lane)*4);
        if (w < 4) {
          unsigned long long pk = 0;
#pragma unroll
          for (int r=0;r<4;r++) {
            float g = sigm(o[r] + p2[r] + igv[r]);
            pk |= (unsigned long long)f2b(g * hv[r]) << (16*r);
          }
          cst64(rhB + (size_t)bb*Hz + 16*n + jl, pk);
        } else {
#pragma unroll
          for (int r=0;r<4;r++) iTl[(jl+r)*65 + bb] = sigm(o[r] + p2[r] + igv[r]);
        }
      }
    }
    gbar(flags, 2*t+1);
    {
      int nt = w & 3, kq = w >> 2;
      int bb = nt*16 + (lane & 15);
      int q  = lane >> 4;
      int jl = q*4;
      float igv[4];
      if (w < 4) {
#pragma unroll
        for (int r=0;r<4;r++) igv[r] = b2f(igt[(size_t)(2048 + 16*n + jl + r)*64 + bb]);
      }
      const unsigned short* bsrc = rhB + (size_t)bb*Hz + q*8;
      bf16x8 bfr[8];
#pragma unroll
      for (int ks=0; ks<8; ks++) bfr[ks] = cldb8(bsrc + (size_t)(kq*8+ks)*32);
      f32x4 acc = {0.f,0.f,0.f,0.f};
#pragma unroll
      for (int ks=0; ks<8; ks++) {
        bf16x8 a = *(const bf16x8*)(wcF + ((size_t)(kq*8+ks)*64 + lane)*8);
        acc = __builtin_amdgcn_mfma_f32_16x16x32_bf16(a, bfr[ks], acc, 0, 0, 0);
      }
      *(f32x4*)(red + ((size_t)w*64 + lane)*4) = acc;
      __syncthreads();
      if (w < 4) {
        f32x4 s0 = *(const f32x4*)(red + ((size_t)w*64+lane)*4);
        f32x4 s1 = *(const f32x4*)(red + ((size_t)(w+4)*64+lane)*4);
        f32x4 s2 = *(const f32x4*)(red + ((size_t)(w+8)*64+lane)*4);
        f32x4 s3 = *(const f32x4*)(red + ((size_t)(w+12)*64+lane)*4);
        float hy4[4];
        unsigned long long pk = 0;
#pragma unroll
        for (int r=0;r<4;r++) {
          float g  = s0[r]+s1[r]+s2[r]+s3[r] + igv[r];
          float ng = tanhf(g);
          float hp = hFl[(jl+r)*65 + bb];
          float iv = iTl[(jl+r)*65 + bb];
          float hy = hp + iv*(ng - hp);
          hy4[r] = hy;
          hFl[(jl+r)*65 + bb] = hy;
          pk |= (unsigned long long)f2b(hy) << (16*r);
        }
        cst64(hB + (size_t)bb*Hz + 16*n + jl, pk);
        float4 ov; ov.x=hy4[0]; ov.y=hy4[1]; ov.z=hy4[2]; ov.w=hy4[3];
        *(float4*)(out + ((size_t)bb*Tz + t)*Hz + 16*n + jl) = ov;
      }
    }
    gbar(flags, 2*t+2);
  }
  {
    int j = tid >> 6, b = tid & 63;
    out[(size_t)Bz*Tz*Hz + (size_t)b*Hz + 16*n + j] = hFl[j*65 + b];
  }
}

extern "C" void kernel_launch(void* const* d_in, const int* in_sizes, int n_in,
                              void* d_out, int out_size, void* d_ws, size_t ws_size,
                              hipStream_t stream)
{
  const float* x   = (const float*)d_in[0];
  const float* h0  = (const float*)d_in[1];
  const float* ctx = (const float*)d_in[2];
  const float* Wi  = (const float*)d_in[3];
  const float* bi  = (const float*)d_in[4];
  const float* Wh  = (const float*)d_in[5];
  const float* bh  = (const float*)d_in[6];
  const float* Wp  = (const float*)d_in[7];
  const float* bp  = (const float*)d_in[8];
  const float* Wc  = (const float*)d_in[9];
  const float* bc  = (const float*)d_in[10];
  float* out = (float*)d_out;

  char* wsp = (char*)d_ws;
  float* pT  = (float*)wsp; wsp += (size_t)G3*64*sizeof(float);       // 768 KB
  unsigned short* hB  = (unsigned short*)wsp; wsp += (size_t)Bz*Hz*2; // 128 KB
  unsigned short* rhB = (unsigned short*)wsp; wsp += (size_t)Bz*Hz*2; // 128 KB
  int* flags = (int*)wsp; wsp += 512;                                 // flags[64]
  unsigned short* igT = (unsigned short*)wsp;                         // 96 MB

  hipMemsetAsync(flags, 0, 512, stream);
  kP  <<<dim3(G3/16),   256,  0, stream>>>(ctx, Wp, bp, bh, bc, bi, pT);
  kI  <<<dim3(64),      256,  0, stream>>>(h0, hB);
  kAm <<<dim3(48,16),   1024, 0, stream>>>(x, Wi, pT, igT);
  krec_full<<<dim3(NBK), 1024, 0, stream>>>(h0, Wh, Wc, igT, hB, rhB, out, flags);
}